// Round 1
// baseline (229.504 us; speedup 1.0000x reference)
//
#include <hip/hip_runtime.h>
#include <stdint.h>

// Problem constants (fixed by setup_inputs in the reference)
#define BATCH 32
#define HDIM  1024
#define WDIM  1024
#define H2    (HDIM / 2)
#define W2    (WDIM / 2)
#define NSTN  256   // stations per batch

// ---------------------------------------------------------------------------
// Wave-64 + LDS block reduction (sum). Block size <= 1024.
// ---------------------------------------------------------------------------
__device__ __forceinline__ float blockReduceSum(float v) {
    #pragma unroll
    for (int off = 32; off > 0; off >>= 1)
        v += __shfl_down(v, off, 64);
    __shared__ float smem[16];
    const int lane = threadIdx.x & 63;
    const int wid  = threadIdx.x >> 6;
    if (lane == 0) smem[wid] = v;
    __syncthreads();
    const int nw = (blockDim.x + 63) >> 6;
    v = (threadIdx.x < nw) ? smem[threadIdx.x] : 0.0f;
    if (wid == 0) {
        #pragma unroll
        for (int off = 8; off > 0; off >>= 1)
            v += __shfl_down(v, off, 64);
    }
    return v;
}

// ---------------------------------------------------------------------------
// Kernel 1: image MSE vs bilinear-upsampled (2x, half-pixel centers) target.
// jax.image.resize 'bilinear' 512->1024: sample_f = i/2 - 0.25.
//   even i=2m: 0.25*t[m-1] + 0.75*t[m]   (clamp m-1 -> edge renorm identical)
//   odd  i=2m+1: 0.75*t[m] + 0.25*t[m+1] (clamp m+1)
// Each thread processes 4 consecutive x pixels (float4 pred load).
// ---------------------------------------------------------------------------
__global__ void img_loss_kernel(const float* __restrict__ pred,
                                const float* __restrict__ tgt,
                                float* __restrict__ acc) {
    const int64_t total4 = (int64_t)BATCH * HDIM * (WDIM / 4);
    float lsum = 0.0f;
    for (int64_t i = (int64_t)blockIdx.x * blockDim.x + threadIdx.x; i < total4;
         i += (int64_t)gridDim.x * blockDim.x) {
        const int x4   = (int)(i % (WDIM / 4));
        const int64_t rest = i / (WDIM / 4);
        const int y = (int)(rest % HDIM);
        const int b = (int)(rest / HDIM);
        const int x0 = x4 * 4;

        const float4 p = *(const float4*)(pred + ((int64_t)b * HDIM + y) * WDIM + x0);

        // vertical interp setup
        const int my = y >> 1;
        int yA, yB; float wyA, wyB;
        if ((y & 1) == 0) { yA = (my - 1 < 0) ? 0 : my - 1; yB = my; wyA = 0.25f; wyB = 0.75f; }
        else              { yA = my; yB = (my + 1 >= H2) ? H2 - 1 : my + 1; wyA = 0.75f; wyB = 0.25f; }

        const float* tA = tgt + ((int64_t)b * H2 + yA) * W2;
        const float* tB = tgt + ((int64_t)b * H2 + yB) * W2;

        const int m0  = x0 >> 1;                        // x0 is even
        const int xm1 = (m0 - 1 < 0) ? 0 : m0 - 1;
        const int xp2 = (m0 + 2 >= W2) ? W2 - 1 : m0 + 2;

        // vertically-interpolated target row at 4 needed columns
        const float r0 = wyA * tA[xm1]    + wyB * tB[xm1];
        const float r1 = wyA * tA[m0]     + wyB * tB[m0];
        const float r2 = wyA * tA[m0 + 1] + wyB * tB[m0 + 1];
        const float r3 = wyA * tA[xp2]    + wyB * tB[xp2];

        // horizontal interp for pixels x0..x0+3 (even,odd,even,odd)
        const float t0 = 0.25f * r0 + 0.75f * r1;
        const float t1 = 0.75f * r1 + 0.25f * r2;
        const float t2 = 0.25f * r1 + 0.75f * r2;
        const float t3 = 0.75f * r2 + 0.25f * r3;

        const float d0 = p.x - t0, d1 = p.y - t1, d2 = p.z - t2, d3 = p.w - t3;
        lsum += d0 * d0 + d1 * d1 + d2 * d2 + d3 * d3;
    }
    const float bs = blockReduceSum(lsum);
    if (threadIdx.x == 0) atomicAdd(acc, bs);
}

// ---------------------------------------------------------------------------
// Kernel 2: station loss. One thread per (b, s). 3x3 clamped-mask box mean.
// pos[b][s][0] = x (column), pos[b][s][1] = y (row).
// ---------------------------------------------------------------------------
__global__ void stn_loss_kernel(const float* __restrict__ pred,
                                const int* __restrict__ pos,
                                const float* __restrict__ runoff,
                                float* __restrict__ acc) {
    const int idx = blockIdx.x * blockDim.x + threadIdx.x;
    float lsum = 0.0f;
    if (idx < BATCH * NSTN) {
        const int b = idx / NSTN;
        const int px = pos[idx * 2 + 0];
        const int py = pos[idx * 2 + 1];
        const float* p = pred + (int64_t)b * HDIM * WDIM;
        float sum = 0.0f; int cnt = 0;
        #pragma unroll
        for (int dy = -1; dy <= 1; ++dy) {
            const int y = py + dy;
            if (y < 0 || y >= HDIM) continue;
            #pragma unroll
            for (int dx = -1; dx <= 1; ++dx) {
                const int x = px + dx;
                if (x < 0 || x >= WDIM) continue;
                sum += p[(int64_t)y * WDIM + x];
                cnt++;
            }
        }
        const float d = sum / (float)cnt - runoff[idx];
        lsum = d * d;
    }
    const float bs = blockReduceSum(lsum);
    if (threadIdx.x == 0) atomicAdd(acc, bs);
}

// ---------------------------------------------------------------------------
// Kernel 3: finalize. out = (total, img_loss, stn_loss)
// ---------------------------------------------------------------------------
__global__ void finalize_kernel(const float* __restrict__ acc,
                                float* __restrict__ out) {
    const float img = acc[0] * (1.0f / ((float)BATCH * HDIM * WDIM));
    const float stn = acc[1] * (1.0f / ((float)BATCH * NSTN));
    out[0] = img + 0.5f * stn;   // IMAGE_W=1.0, STATION_W=0.5
    out[1] = img;
    out[2] = stn;
}

extern "C" void kernel_launch(void* const* d_in, const int* in_sizes, int n_in,
                              void* d_out, int out_size, void* d_ws, size_t ws_size,
                              hipStream_t stream) {
    const float* pred   = (const float*)d_in[0];
    const float* tgt    = (const float*)d_in[1];
    const int*   pos    = (const int*)d_in[2];
    const float* runoff = (const float*)d_in[3];
    float* out = (float*)d_out;
    float* acc = (float*)d_ws;   // acc[0] = img sum, acc[1] = stn sum

    hipMemsetAsync(acc, 0, 2 * sizeof(float), stream);

    // Image loss: 8.39M float4 groups, grid-stride. 2048 blocks x 256 = 8 wg/CU.
    img_loss_kernel<<<2048, 256, 0, stream>>>(pred, tgt, acc);

    // Station loss: 8192 threads.
    stn_loss_kernel<<<(BATCH * NSTN + 255) / 256, 256, 0, stream>>>(pred, pos, runoff, acc + 1);

    finalize_kernel<<<1, 1, 0, stream>>>(acc, out);
}